// Round 8
// baseline (633.504 us; speedup 1.0000x reference)
//
#include <hip/hip_runtime.h>
#include <hip/hip_cooperative_groups.h>
#include <math.h>

namespace cg = cooperative_groups;

#define B_ 32
#define H_ 112
#define W_ 112
#define C_ 192
#define C4 (C_/4)            // 48
#define NPOS (B_*H_*W_)      // 401408
#define NBLK 1792            // 7 blocks/CU exactly; 1792 = 8*224 (XCD-bijective)
#define RPI (H_/2)           // 56 row-pairs per image
#define HALO 3
#define SWP 120              // padded LDS width (118 used)

typedef float nf4 __attribute__((ext_vector_type(4)));

// XCD swizzle: HW round-robins blockIdx across 8 XCDs; relabel so each XCD
// owns 224 CONTIGUOUS bids (neighboring row-pairs share an XCD's L2).
__device__ __forceinline__ int swz(int raw) { return (raw & 7) * (NBLK / 8) + (raw >> 3); }

// ---- Phase A: channel mean/max for this block's 2 image rows -> ws2 ----
// 224 positions = 14 iters x (4 waves x 4 groups); 16 lanes per position.
__device__ __forceinline__ void phaseA(const float* __restrict__ x,
                                       float2* __restrict__ ws2, int bid) {
    const int tid  = threadIdx.x;
    const int wv   = tid >> 6;
    const int lane = tid & 63;
    const int sub  = lane & 15;
    const int grp  = lane >> 4;
    const int pbase = bid * 224 + wv * 4 + grp;
    #pragma unroll
    for (int it = 0; it < 14; ++it) {
        const int p = pbase + it * 16;
        const nf4* xp = (const nf4*)x + (size_t)p * C4;
        nf4 a0 = __builtin_nontemporal_load(xp + sub);
        nf4 a1 = __builtin_nontemporal_load(xp + sub + 16);
        nf4 a2 = __builtin_nontemporal_load(xp + sub + 32);
        float s = ((a0[0]+a0[1]) + (a0[2]+a0[3]))
                + ((a1[0]+a1[1]) + (a1[2]+a1[3]))
                + ((a2[0]+a2[1]) + (a2[2]+a2[3]));
        float m0 = fmaxf(fmaxf(a0[0], a0[1]), fmaxf(a0[2], a0[3]));
        float m1 = fmaxf(fmaxf(a1[0], a1[1]), fmaxf(a1[2], a1[3]));
        float m2 = fmaxf(fmaxf(a2[0], a2[1]), fmaxf(a2[2], a2[3]));
        float m  = fmaxf(m0, fmaxf(m1, m2));
        #pragma unroll
        for (int off = 8; off > 0; off >>= 1) {
            s += __shfl_xor(s, off);
            m = fmaxf(m, __shfl_xor(m, off));
        }
        if (sub == 0) {
            float2 r; r.x = s * (1.0f / (float)C_); r.y = m;
            ws2[p] = r;
        }
    }
}

// ---- Phase B: 7x7 conv + sigmoid on ws2, then out = x * att (2 rows) ----
__device__ __forceinline__ void phaseB(const float* __restrict__ x,
                                       const float2* __restrict__ ws2,
                                       const float* __restrict__ w,
                                       float* __restrict__ out, int bid) {
    __shared__ float2 sm[2*HALO + 2][SWP];   // 8 x 120
    __shared__ float  sw[98];
    __shared__ float  satt[2 * W_];

    const int tid = threadIdx.x;
    const int b   = bid / RPI;
    const int y0  = (bid - b * RPI) * 2;

    if (tid < 98) sw[tid] = w[tid];

    // stage 8 halo rows x 118 cols of (avg,max); zero outside image
    const float2* wsb = ws2 + (size_t)b * (H_ * W_);
    for (int i = tid; i < 8 * (W_ + 2*HALO); i += 256) {
        const int r  = i / (W_ + 2*HALO);
        const int c  = i - r * (W_ + 2*HALO);
        const int yy = y0 + r - HALO;
        const int xx = c - HALO;
        float2 v = make_float2(0.0f, 0.0f);
        if (yy >= 0 && yy < H_ && xx >= 0 && xx < W_)
            v = wsb[yy * W_ + xx];
        sm[r][c] = v;
    }
    __syncthreads();

    if (tid < 2 * W_) {
        const int r  = tid / W_;
        const int cl = tid - r * W_;
        float acc = 0.0f;
        #pragma unroll
        for (int ky = 0; ky < 7; ++ky) {
            #pragma unroll
            for (int kx = 0; kx < 7; ++kx) {
                float2 am = sm[r + ky][cl + kx];
                acc = fmaf(am.x, sw[(ky * 7 + kx) * 2 + 0], acc);
                acc = fmaf(am.y, sw[(ky * 7 + kx) * 2 + 1], acc);
            }
        }
        satt[tid] = 1.0f / (1.0f + __expf(-acc));
    }
    __syncthreads();

    // stream multiply: 2*112*48 = 10752 float4 = 42 exact iters of 256
    const size_t base4 = ((size_t)b * H_ + y0) * W_ * C4;
    const nf4* xr = (const nf4*)x + base4;
    nf4*       o  = (nf4*)out + base4;
    #pragma unroll 2
    for (int k = 0; k < (2 * W_ * C4) / 256; ++k) {
        const int f = tid + k * 256;
        nf4 v = __builtin_nontemporal_load(xr + f);
        v = v * satt[f / C4];
        __builtin_nontemporal_store(v, o + f);
    }
}

// ---- Cooperative fused kernel: phase A || grid.sync || phase B ----
__global__ __launch_bounds__(256, 7) void spatial_coop(const float* __restrict__ x,
                                                       const float* __restrict__ w,
                                                       float* __restrict__ out,
                                                       float2* __restrict__ ws2) {
    const int bid = swz((int)blockIdx.x);
    phaseA(x, ws2, bid);
    __threadfence();
    cg::this_grid().sync();
    phaseB(x, ws2, w, out, bid);
}

// ---- Fallback plain kernels (≡ champion two-kernel path) ----
__global__ __launch_bounds__(256, 7) void phaseA_kernel(const float* __restrict__ x,
                                                        float2* __restrict__ ws2) {
    phaseA(x, ws2, swz((int)blockIdx.x));
}
__global__ __launch_bounds__(256, 7) void phaseB_kernel(const float* __restrict__ x,
                                                        const float2* __restrict__ ws2,
                                                        const float* __restrict__ w,
                                                        float* __restrict__ out) {
    phaseB(x, ws2, w, out, swz((int)blockIdx.x));
}

extern "C" void kernel_launch(void* const* d_in, const int* in_sizes, int n_in,
                              void* d_out, int out_size, void* d_ws, size_t ws_size,
                              hipStream_t stream) {
    const float* x = (const float*)d_in[0];
    const float* w = (const float*)d_in[1];
    float* out = (float*)d_out;
    float2* ws2 = (float2*)d_ws;   // NPOS float2 = 3.2 MB

    void* args[] = { (void*)&x, (void*)&w, (void*)&out, (void*)&ws2 };
    hipError_t err = hipLaunchCooperativeKernel((const void*)spatial_coop,
                                                dim3(NBLK), dim3(256), args, 0, stream);
    if (err != hipSuccess) {
        // R5 lesson: never trust a silent coop failure. Fall back to the
        // proven two-kernel path (same device code, plain launches).
        phaseA_kernel<<<NBLK, 256, 0, stream>>>(x, ws2);
        phaseB_kernel<<<NBLK, 256, 0, stream>>>(x, ws2, w, out);
    }
}

// Round 9
// 147.403 us; speedup vs baseline: 4.2978x; 4.2978x over previous
//
#include <hip/hip_runtime.h>
#include <math.h>

#define B_ 32
#define H_ 112
#define W_ 112
#define C_ 192
#define NPOS (B_*H_*W_)      // 401408
#define C4 (C_/4)            // 48
#define HALO 3
#define SW (W_ + 2*HALO)     // 118

typedef float nf4 __attribute__((ext_vector_type(4)));

// ---------------- Kernel A: per-position channel mean + max ----------------
// 4 positions per wave, 16 lanes per position, 3 float4 per lane.
__global__ __launch_bounds__(256) void reduce_kernel(const float* __restrict__ x,
                                                     float2* __restrict__ ws2) {
    const int wave = threadIdx.x >> 6;
    const int lane = threadIdx.x & 63;
    const int sub  = lane & 15;
    const int p = blockIdx.x * 16 + wave * 4 + (lane >> 4);  // grid exact: NPOS/16

    const float4* xp = (const float4*)(x + (size_t)p * C_);
    float4 v0 = xp[sub];
    float4 v1 = xp[sub + 16];
    float4 v2 = xp[sub + 32];
    float s = (v0.x + v0.y + v0.z + v0.w)
            + (v1.x + v1.y + v1.z + v1.w)
            + (v2.x + v2.y + v2.z + v2.w);
    float m0 = fmaxf(fmaxf(v0.x, v0.y), fmaxf(v0.z, v0.w));
    float m1 = fmaxf(fmaxf(v1.x, v1.y), fmaxf(v1.z, v1.w));
    float m2 = fmaxf(fmaxf(v2.x, v2.y), fmaxf(v2.z, v2.w));
    float m  = fmaxf(m0, fmaxf(m1, m2));
    #pragma unroll
    for (int off = 8; off > 0; off >>= 1) {
        s += __shfl_xor(s, off);
        m = fmaxf(m, __shfl_xor(m, off));
    }
    if (sub == 0) {
        float2 r;
        r.x = s * (1.0f / (float)C_);
        r.y = m;
        ws2[p] = r;
    }
}

// ------- Kernel B: fused 7x7 conv + sigmoid + broadcast multiply -----------
// One block per (b,y) row, processed in REVERSED order so the first x reads
// hit the tail of x still resident in L3 from kernel A. R9 change: x loads
// are REGULAR (NT loads bypassed the cache and defeated the reversal).
// Stores stay non-temporal (dead data, don't evict not-yet-read x).
__global__ __launch_bounds__(256) void fused_kernel(const float* __restrict__ x,
                                                    const float2* __restrict__ ws2,
                                                    const float* __restrict__ w,
                                                    float* __restrict__ out) {
    __shared__ float2 sm[7][SW];   // (avg,max) halo tile, zero-padded in x
    __shared__ float  sw[98];
    __shared__ float  satt[W_];

    const int tid = threadIdx.x;
    const int rb = (B_ * H_ - 1) - (int)blockIdx.x;   // reversed traversal
    const int b  = rb / H_;
    const int y  = rb - b * H_;

    if (tid < 98) sw[tid] = w[tid];

    // stage 7 rows x 118 cols of (avg,max), zero outside the image
    const float2* wsb = ws2 + (size_t)b * (H_ * W_);
    for (int idx = tid; idx < 7 * SW; idx += 256) {
        const int r   = idx / SW;
        const int col = idx - r * SW;
        const int yy  = y + r - HALO;
        const int xx  = col - HALO;
        float2 v = make_float2(0.0f, 0.0f);
        if (yy >= 0 && yy < H_ && xx >= 0 && xx < W_)
            v = wsb[yy * W_ + xx];
        sm[r][col] = v;
    }
    __syncthreads();

    // conv: 112 threads, no bounds checks (halo pre-zeroed)
    if (tid < W_) {
        float acc = 0.0f;
        #pragma unroll
        for (int ky = 0; ky < 7; ++ky) {
            #pragma unroll
            for (int kx = 0; kx < 7; ++kx) {
                float2 am = sm[ky][tid + kx];
                acc = fmaf(am.x, sw[(ky * 7 + kx) * 2 + 0], acc);
                acc = fmaf(am.y, sw[(ky * 7 + kx) * 2 + 1], acc);
            }
        }
        satt[tid] = 1.0f / (1.0f + __expf(-acc));
    }
    __syncthreads();

    // multiply: full row = 112*48 = 5376 float4 = 21 exact iters of 256 threads
    const size_t row4 = ((size_t)b * H_ + y) * W_ * C4;   // float4 index of row
    const nf4* xr = (const nf4*)x + row4;
    nf4* orow = (nf4*)out + row4;
    #pragma unroll
    for (int k = 0; k < (W_ * C4) / 256; ++k) {
        const int f4  = tid + k * 256;
        const int pos = f4 / C4;
        nf4 v = xr[f4];                              // REGULAR load: want L3 tail hit
        v = v * satt[pos];
        __builtin_nontemporal_store(v, &orow[f4]);   // dead data: don't pollute L3
    }
}

extern "C" void kernel_launch(void* const* d_in, const int* in_sizes, int n_in,
                              void* d_out, int out_size, void* d_ws, size_t ws_size,
                              hipStream_t stream) {
    const float* x = (const float*)d_in[0];
    const float* w = (const float*)d_in[1];
    float* out = (float*)d_out;

    float2* ws2 = (float2*)d_ws;   // NPOS float2 = 3.2 MB

    // Kernel A: 16 positions per block (4 waves x 4 positions)
    reduce_kernel<<<NPOS / 16, 256, 0, stream>>>(x, ws2);

    // Kernel B: one block per (b,y) row, reversed inside the kernel
    fused_kernel<<<B_ * H_, 256, 0, stream>>>(x, ws2, w, out);
}